// Round 1
// baseline (676.733 us; speedup 1.0000x reference)
//
#include <hip/hip_runtime.h>

// SpectralConv2d as 4 dense partial-DFT GEMMs (bf16 MFMA) + fp32 channel mix.
// B=16, Cin=Cout=64, H=W=256, modes 32x32.
//
// Round-1 changes vs 711.4us baseline:
//  * fwd: stage-A A/B fragments built DIRECTLY from global (x via float4+f2b,
//    F2t via short8 from L2-resident table) -> no lA/lB staging, 1 barrier
//    instead of 9. F1e read directly from global (wave-disjoint rows; LDS
//    staging bought no reuse). LDS 136KB -> 32.5KB (1 -> 3-4 blocks/CU).
//  * inv: G1/G2 tables read directly from global (wave-disjoint rows).
//    LDS 132KB -> 40KB (1 -> 4 blocks/CU). Mx transposed to [ky][kx2] during
//    4KB LDS staging so stage-C B-fragments are ds_read_b128 instead of
//    32 scalar ds_read_u16.
//  * lT/lZ padded +8 ushorts/row (144B / 1040B stride, 16B aligned) to kill
//    the 16-way bank conflicts of 128B-stride ds_read_b128.
// All MFMA operand values are bit-identical to the verified baseline.
//
// ws layout (bytes):
//   [0      ) F2t  ushort[64][256]   : B-op of stage A   (32 KB)
//   [32768  ) F1e  ushort[64][512]   : A-op of stage B   (64 KB)
//   [98304  ) G1   ushort[512][64]   : A-op of stage C   (64 KB)
//   [163840 ) G2t  ushort[256][64]   : B-op of stage D   (32 KB)
//   [196608 ) Y    float[16][64][64][32]  (8 MB)
//   [8585216) Mx   ushort[16][64][64][32] (4 MB)
//   total 12779520 B

#define H_ 256
#define W_ 256

typedef short short8 __attribute__((ext_vector_type(8)));
typedef float floatx4 __attribute__((ext_vector_type(4)));

static __device__ __forceinline__ unsigned short f2b(float f) {
    union { float f; unsigned int u; } v; v.f = f;
    unsigned int r = v.u + 0x7FFFu + ((v.u >> 16) & 1u);
    return (unsigned short)(r >> 16);
}

// ---------------- K0: twiddle tables (fp64 -> bf16) ----------------
__global__ void build_tables(unsigned short* ws) {
    int k = blockIdx.x;      // mode index 0..31
    int n = threadIdx.x;     // position 0..255
    int u = (k * n) & 255;
    double ang = 6.283185307179586476925286766559 * (double)u / 256.0;
    float c = (float)cos(ang), s = (float)sin(ang);
    unsigned short bc = f2b(c), bs = f2b(s), bns = f2b(-s);
    unsigned short* F2t = ws;                    // [2ky+c][w]
    unsigned short* F1e = ws + 16384;            // [2kx+c][2h+c']
    unsigned short* G1  = ws + 16384 + 32768;    // [2h+c'][2kx+c]
    unsigned short* G2t = ws + 16384 + 65536;    // [w][2ky+c]

    // Stage A (forward DFT over w, e^{-i}): Tr=sum x*cos, Ti=-sum x*sin
    F2t[(2 * k) * 256 + n]     = bc;
    F2t[(2 * k + 1) * 256 + n] = bns;
    // Stage B (forward DFT over h, e^{-i}, complex T):
    // Yre = sum c*Tr + s*Ti ; Yim = sum c*Ti - s*Tr
    F1e[(2 * k) * 512 + 2 * n]         = bc;
    F1e[(2 * k) * 512 + 2 * n + 1]     = bs;
    F1e[(2 * k + 1) * 512 + 2 * n]     = bns;
    F1e[(2 * k + 1) * 512 + 2 * n + 1] = bc;
    // Stage C (inverse DFT over kx, e^{+i}): Zre = c*Mr - s*Mi ; Zim = s*Mr + c*Mi
    G1[(2 * n) * 64 + 2 * k]         = bc;
    G1[(2 * n) * 64 + 2 * k + 1]     = bns;
    G1[(2 * n + 1) * 64 + 2 * k]     = bs;
    G1[(2 * n + 1) * 64 + 2 * k + 1] = bc;
    // Stage D (irfft over ky): out = sum fac*(Zr*cos - Zi*sin), fac = ky?2:1
    float fac = (k == 0) ? 1.f : 2.f;
    G2t[n * 64 + 2 * k]     = f2b(fac * c);
    G2t[n * 64 + 2 * k + 1] = f2b(-fac * s);
}

// ---------------- K1: forward, fused stages A+B, one block per (b,i) ----------------
// LDS: only lT (32.5 KB). Stage-A operands stream straight from global.
__global__ __launch_bounds__(256) void fwd_kernel(const float* __restrict__ x,
                                                  const unsigned short* __restrict__ ws_u,
                                                  float* __restrict__ Y) {
    __shared__ __align__(16) unsigned short lT[32 * 520];   // [ky][h2 padded] 32.5 KB
    const int tid = threadIdx.x;
    const int wave = tid >> 6, lane = tid & 63;
    const int lm = lane & 15, lq = lane >> 4;
    const int bi = blockIdx.x;

    const float* xg = x + (size_t)bi * (H_ * W_);
    const unsigned short* F2tg = ws_u;           // [64 ky2][256 w], L2-resident
    const unsigned short* F1eg = ws_u + 16384;   // [64 kx2][512 h2], L2-resident

    floatx4 acc[4][4];
    for (int a = 0; a < 4; ++a)
        for (int b = 0; b < 4; ++b) acc[a][b] = (floatx4){0.f, 0.f, 0.f, 0.f};

    // Stage A: T[h][ky2] = sum_w x[h][w] * F2t[ky2][w]   (M=256,N=64,K=256)
    for (int kc = 0; kc < 4; ++kc) {
        for (int kk = 0; kk < 2; ++kk) {
            short8 af[4], bf[4];
            for (int a = 0; a < 4; ++a) {
                const float* ap = xg + (((wave * 4 + a) * 16 + lm) * 256 + kc * 64 + kk * 32 + lq * 8);
                const float4 v0 = *(const float4*)ap;
                const float4 v1 = *(const float4*)(ap + 4);
                short8 t;
                t[0] = (short)f2b(v0.x); t[1] = (short)f2b(v0.y);
                t[2] = (short)f2b(v0.z); t[3] = (short)f2b(v0.w);
                t[4] = (short)f2b(v1.x); t[5] = (short)f2b(v1.y);
                t[6] = (short)f2b(v1.z); t[7] = (short)f2b(v1.w);
                af[a] = t;
            }
            for (int b = 0; b < 4; ++b)
                bf[b] = *(const short8*)(F2tg + (b * 16 + lm) * 256 + kc * 64 + kk * 32 + lq * 8);
            for (int a = 0; a < 4; ++a)
                for (int b = 0; b < 4; ++b)
                    acc[a][b] = __builtin_amdgcn_mfma_f32_16x16x32_bf16(af[a], bf[b], acc[a][b], 0, 0, 0);
        }
    }
    // write T2 into lT as [ky][h2=2h+c] bf16 (stage B's B-operand layout)
    for (int a = 0; a < 4; ++a) {
        int mbase = (wave * 4 + a) * 16 + lq * 4;
        for (int b = 0; b < 4; ++b) {
            int col = b * 16 + lm;            // 2ky+c
            int ky = col >> 1, c = col & 1;
            for (int r = 0; r < 4; ++r) {
                int h = mbase + r;
                lT[ky * 520 + 2 * h + c] = f2b(acc[a][b][r]);
            }
        }
    }
    __syncthreads();
    // Stage B: Y[64][32] = F1e[64][512] x T2[512][32]; wave -> m-tile, nt 0..1
    floatx4 acc2[2];
    acc2[0] = (floatx4){0.f, 0.f, 0.f, 0.f};
    acc2[1] = (floatx4){0.f, 0.f, 0.f, 0.f};
    for (int ks = 0; ks < 16; ++ks) {
        short8 af = *(const short8*)(F1eg + (wave * 16 + lm) * 512 + ks * 32 + lq * 8);
        for (int b = 0; b < 2; ++b) {
            short8 bf = *(const short8*)(lT + (b * 16 + lm) * 520 + ks * 32 + lq * 8);
            acc2[b] = __builtin_amdgcn_mfma_f32_16x16x32_bf16(af, bf, acc2[b], 0, 0, 0);
        }
    }
    float* Yg = Y + (size_t)bi * (64 * 32);
    for (int b = 0; b < 2; ++b) {
        int colk = b * 16 + lm;               // ky
        int mrow = wave * 16 + lq * 4;        // kx2
        for (int r = 0; r < 4; ++r)
            Yg[(mrow + r) * 32 + colk] = acc2[b][r];
    }
}

// ---------------- K2: channel mix (fp32), one block per (b,kx) ----------------
__global__ __launch_bounds__(256) void mix_kernel(const float* __restrict__ Wg,
                                                  const float* __restrict__ Y,
                                                  unsigned short* __restrict__ Mx) {
    __shared__ float Yb[64][2][32];   // [i][c][ky]
    const int b = blockIdx.x, kx = blockIdx.y;
    const int tid = threadIdx.x;
    for (int q = 0; q < 16; ++q) {
        int idx = q * 256 + tid;      // 0..4095
        int i = idx >> 6, rem = idx & 63, c = rem >> 5, ky = rem & 31;
        Yb[i][c][ky] = Y[(((size_t)b * 64 + i) * 64 + (2 * kx + c)) * 32 + ky];
    }
    __syncthreads();
    const int ky = tid & 31, o2 = tid >> 5;   // o2 0..7
    const float scale = 1.f / 65536.f;        // 1/(H*W): ifft+irfft normalization
    for (int oo = 0; oo < 8; ++oo) {
        int o = o2 * 8 + oo;
        float ar = 0.f, ai = 0.f;
        for (int i = 0; i < 64; ++i) {
            float w = Wg[(size_t)(i * 64 + o) * 1024 + kx * 32 + ky];
            ar += Yb[i][0][ky] * w;
            ai += Yb[i][1][ky] * w;
        }
        unsigned short* dst = Mx + ((size_t)(b * 64 + o) * 64 + 2 * kx) * 32 + ky;
        dst[0]  = f2b(ar * scale);
        dst[32] = f2b(ai * scale);
    }
}

// ---------------- K3: inverse, fused stages C+D, one block per (b,o) ----------------
// LDS: lMx 4KB (transposed to [ky][kx2]) + lZ 36KB = 40KB -> 4 blocks/CU.
__global__ __launch_bounds__(256) void inv_kernel(const unsigned short* __restrict__ ws_u,
                                                  const unsigned short* __restrict__ Mx,
                                                  const float* __restrict__ bias,
                                                  float* __restrict__ out) {
    __shared__ __align__(16) unsigned short lMx[32 * 64];   // 4 KB  [ky][kx2]
    __shared__ __align__(16) unsigned short lZ[256 * 72];   // 36 KB [h][ky2 padded]
    const int tid = threadIdx.x;
    const int wave = tid >> 6, lane = tid & 63;
    const int lm = lane & 15, lq = lane >> 4;
    const int bo = blockIdx.x;
    const int o = bo & 63;

    const unsigned short* G1g = ws_u + 49152;    // [512 h2][64 kx2], L2-resident
    const unsigned short* G2g = ws_u + 81920;    // [256 w][64 ky2],  L2-resident

    {   // stage Mx (old layout [kx2][ky]) -> lMx transposed [ky][kx2]
        short8 v = *(const short8*)(Mx + (size_t)bo * 2048 + tid * 8);
        int kx2 = tid >> 2, kyb = (tid & 3) * 8;
        for (int e = 0; e < 8; ++e)
            lMx[(kyb + e) * 64 + kx2] = (unsigned short)v[e];
    }
    __syncthreads();

    // Stage C: Z2[512][32] = G1[512][64] x Mx2[64][32]; wave -> 8 m-tiles, 2 n-tiles
    {
        floatx4 accc[8][2];
        for (int a = 0; a < 8; ++a)
            for (int b = 0; b < 2; ++b) accc[a][b] = (floatx4){0.f, 0.f, 0.f, 0.f};
        for (int ks = 0; ks < 2; ++ks) {
            short8 bf[2];
            for (int b = 0; b < 2; ++b)
                bf[b] = *(const short8*)(lMx + (b * 16 + lm) * 64 + ks * 32 + lq * 8);
            for (int a = 0; a < 8; ++a) {
                int mt = wave * 8 + a;
                short8 af = *(const short8*)(G1g + (mt * 16 + lm) * 64 + ks * 32 + lq * 8);
                for (int b = 0; b < 2; ++b)
                    accc[a][b] = __builtin_amdgcn_mfma_f32_16x16x32_bf16(af, bf[b], accc[a][b], 0, 0, 0);
            }
        }
        // Z -> lZ [h][2ky+c]  (stage D's A-operand layout), padded stride 72
        for (int a = 0; a < 8; ++a) {
            int mbase = (wave * 8 + a) * 16 + lq * 4;
            for (int b = 0; b < 2; ++b) {
                int ky = b * 16 + lm;
                for (int r = 0; r < 4; ++r) {
                    int m = mbase + r;        // h2 = 2h + c
                    int h = m >> 1, c = m & 1;
                    lZ[h * 72 + 2 * ky + c] = f2b(accc[a][b][r]);
                }
            }
        }
    }
    __syncthreads();

    const float bv = bias[o];
    float* og = out + (size_t)bo * (H_ * W_);
    // Stage D: out[256][256] = Z2[256][64] x G2t'[64][256], in 4 h-strips of 64
    for (int s = 0; s < 4; ++s) {
        floatx4 accd[4][4];
        for (int a = 0; a < 4; ++a)
            for (int b = 0; b < 4; ++b) accd[a][b] = (floatx4){0.f, 0.f, 0.f, 0.f};
        for (int ks = 0; ks < 2; ++ks) {
            short8 af[4], bf[4];
            for (int a = 0; a < 4; ++a) {
                int mt = s * 4 + a;
                af[a] = *(const short8*)(lZ + (mt * 16 + lm) * 72 + ks * 32 + lq * 8);
            }
            for (int b = 0; b < 4; ++b) {
                int nt = wave * 4 + b;
                bf[b] = *(const short8*)(G2g + (nt * 16 + lm) * 64 + ks * 32 + lq * 8);
            }
            for (int a = 0; a < 4; ++a)
                for (int b = 0; b < 4; ++b)
                    accd[a][b] = __builtin_amdgcn_mfma_f32_16x16x32_bf16(af[a], bf[b], accd[a][b], 0, 0, 0);
        }
        for (int a = 0; a < 4; ++a) {
            int hbase = (s * 4 + a) * 16 + lq * 4;
            for (int b = 0; b < 4; ++b) {
                int w = (wave * 4 + b) * 16 + lm;
                for (int r = 0; r < 4; ++r)
                    og[(hbase + r) * 256 + w] = accd[a][b][r] + bv;
            }
        }
    }
}

extern "C" void kernel_launch(void* const* d_in, const int* in_sizes, int n_in,
                              void* d_out, int out_size, void* d_ws, size_t ws_size,
                              hipStream_t stream) {
    const float* x    = (const float*)d_in[0];
    const float* w    = (const float*)d_in[1];
    const float* bias = (const float*)d_in[2];
    float* out = (float*)d_out;
    unsigned short* ws_u = (unsigned short*)d_ws;
    float* Y = (float*)((char*)d_ws + 196608);
    unsigned short* Mx = (unsigned short*)((char*)d_ws + 8585216);

    build_tables<<<32, 256, 0, stream>>>(ws_u);
    fwd_kernel<<<1024, 256, 0, stream>>>(x, ws_u, Y);
    mix_kernel<<<dim3(16, 32), 256, 0, stream>>>(w, Y, Mx);
    inv_kernel<<<1024, 256, 0, stream>>>(ws_u, Mx, bias, out);
}

// Round 2
// 525.739 us; speedup vs baseline: 1.2872x; 1.2872x over previous
//
#include <hip/hip_runtime.h>

// SpectralConv2d as 4 dense partial-DFT GEMMs (bf16 MFMA) + fp32 channel mix.
// B=16, Cin=Cout=64, H=W=256, modes 32x32.
//
// Round-2 change: mix_kernel restructured. Old: one block per (b,kx), weights
// re-fetched 16x with 256KB-stride scalar reads, 205us at 4.6% HBM / 11.5% occ.
// New: one block per (kx,ky) mode (1024 blocks, fully resident); 16KB W-slice
// + 8KB Y-slice gathered to LDS (24 independent loads/thread), fp32 compute
// from LDS with identical i-ascending summation order. Each W element read by
// exactly one block. XCD-bijective swizzle colocates all ky of a kx so 64B
// weight lines (16 ky wide) are fetched once.
//
// ws layout (bytes):
//   [0      ) F2t  ushort[64][256]   : B-op of stage A   (32 KB)
//   [32768  ) F1e  ushort[64][512]   : A-op of stage B   (64 KB)
//   [98304  ) G1   ushort[512][64]   : A-op of stage C   (64 KB)
//   [163840 ) G2t  ushort[256][64]   : B-op of stage D   (32 KB)
//   [196608 ) Y    float[16][64][64][32]  (8 MB)
//   [8585216) Mx   ushort[16][64][64][32] (4 MB)
//   total 12779520 B

#define H_ 256
#define W_ 256

typedef short short8 __attribute__((ext_vector_type(8)));
typedef float floatx4 __attribute__((ext_vector_type(4)));

static __device__ __forceinline__ unsigned short f2b(float f) {
    union { float f; unsigned int u; } v; v.f = f;
    unsigned int r = v.u + 0x7FFFu + ((v.u >> 16) & 1u);
    return (unsigned short)(r >> 16);
}

// ---------------- K0: twiddle tables (fp64 -> bf16) ----------------
__global__ void build_tables(unsigned short* ws) {
    int k = blockIdx.x;      // mode index 0..31
    int n = threadIdx.x;     // position 0..255
    int u = (k * n) & 255;
    double ang = 6.283185307179586476925286766559 * (double)u / 256.0;
    float c = (float)cos(ang), s = (float)sin(ang);
    unsigned short bc = f2b(c), bs = f2b(s), bns = f2b(-s);
    unsigned short* F2t = ws;                    // [2ky+c][w]
    unsigned short* F1e = ws + 16384;            // [2kx+c][2h+c']
    unsigned short* G1  = ws + 16384 + 32768;    // [2h+c'][2kx+c]
    unsigned short* G2t = ws + 16384 + 65536;    // [w][2ky+c]

    // Stage A (forward DFT over w, e^{-i}): Tr=sum x*cos, Ti=-sum x*sin
    F2t[(2 * k) * 256 + n]     = bc;
    F2t[(2 * k + 1) * 256 + n] = bns;
    // Stage B (forward DFT over h, e^{-i}, complex T):
    // Yre = sum c*Tr + s*Ti ; Yim = sum c*Ti - s*Tr
    F1e[(2 * k) * 512 + 2 * n]         = bc;
    F1e[(2 * k) * 512 + 2 * n + 1]     = bs;
    F1e[(2 * k + 1) * 512 + 2 * n]     = bns;
    F1e[(2 * k + 1) * 512 + 2 * n + 1] = bc;
    // Stage C (inverse DFT over kx, e^{+i}): Zre = c*Mr - s*Mi ; Zim = s*Mr + c*Mi
    G1[(2 * n) * 64 + 2 * k]         = bc;
    G1[(2 * n) * 64 + 2 * k + 1]     = bns;
    G1[(2 * n + 1) * 64 + 2 * k]     = bs;
    G1[(2 * n + 1) * 64 + 2 * k + 1] = bc;
    // Stage D (irfft over ky): out = sum fac*(Zr*cos - Zi*sin), fac = ky?2:1
    float fac = (k == 0) ? 1.f : 2.f;
    G2t[n * 64 + 2 * k]     = f2b(fac * c);
    G2t[n * 64 + 2 * k + 1] = f2b(-fac * s);
}

// ---------------- K1: forward, fused stages A+B, one block per (b,i) ----------------
// LDS: only lT (32.5 KB). Stage-A operands stream straight from global.
__global__ __launch_bounds__(256) void fwd_kernel(const float* __restrict__ x,
                                                  const unsigned short* __restrict__ ws_u,
                                                  float* __restrict__ Y) {
    __shared__ __align__(16) unsigned short lT[32 * 520];   // [ky][h2 padded] 32.5 KB
    const int tid = threadIdx.x;
    const int wave = tid >> 6, lane = tid & 63;
    const int lm = lane & 15, lq = lane >> 4;
    const int bi = blockIdx.x;

    const float* xg = x + (size_t)bi * (H_ * W_);
    const unsigned short* F2tg = ws_u;           // [64 ky2][256 w], L2-resident
    const unsigned short* F1eg = ws_u + 16384;   // [64 kx2][512 h2], L2-resident

    floatx4 acc[4][4];
    for (int a = 0; a < 4; ++a)
        for (int b = 0; b < 4; ++b) acc[a][b] = (floatx4){0.f, 0.f, 0.f, 0.f};

    // Stage A: T[h][ky2] = sum_w x[h][w] * F2t[ky2][w]   (M=256,N=64,K=256)
    for (int kc = 0; kc < 4; ++kc) {
        for (int kk = 0; kk < 2; ++kk) {
            short8 af[4], bf[4];
            for (int a = 0; a < 4; ++a) {
                const float* ap = xg + (((wave * 4 + a) * 16 + lm) * 256 + kc * 64 + kk * 32 + lq * 8);
                const float4 v0 = *(const float4*)ap;
                const float4 v1 = *(const float4*)(ap + 4);
                short8 t;
                t[0] = (short)f2b(v0.x); t[1] = (short)f2b(v0.y);
                t[2] = (short)f2b(v0.z); t[3] = (short)f2b(v0.w);
                t[4] = (short)f2b(v1.x); t[5] = (short)f2b(v1.y);
                t[6] = (short)f2b(v1.z); t[7] = (short)f2b(v1.w);
                af[a] = t;
            }
            for (int b = 0; b < 4; ++b)
                bf[b] = *(const short8*)(F2tg + (b * 16 + lm) * 256 + kc * 64 + kk * 32 + lq * 8);
            for (int a = 0; a < 4; ++a)
                for (int b = 0; b < 4; ++b)
                    acc[a][b] = __builtin_amdgcn_mfma_f32_16x16x32_bf16(af[a], bf[b], acc[a][b], 0, 0, 0);
        }
    }
    // write T2 into lT as [ky][h2=2h+c] bf16 (stage B's B-operand layout)
    for (int a = 0; a < 4; ++a) {
        int mbase = (wave * 4 + a) * 16 + lq * 4;
        for (int b = 0; b < 4; ++b) {
            int col = b * 16 + lm;            // 2ky+c
            int ky = col >> 1, c = col & 1;
            for (int r = 0; r < 4; ++r) {
                int h = mbase + r;
                lT[ky * 520 + 2 * h + c] = f2b(acc[a][b][r]);
            }
        }
    }
    __syncthreads();
    // Stage B: Y[64][32] = F1e[64][512] x T2[512][32]; wave -> m-tile, nt 0..1
    floatx4 acc2[2];
    acc2[0] = (floatx4){0.f, 0.f, 0.f, 0.f};
    acc2[1] = (floatx4){0.f, 0.f, 0.f, 0.f};
    for (int ks = 0; ks < 16; ++ks) {
        short8 af = *(const short8*)(F1eg + (wave * 16 + lm) * 512 + ks * 32 + lq * 8);
        for (int b = 0; b < 2; ++b) {
            short8 bf = *(const short8*)(lT + (b * 16 + lm) * 520 + ks * 32 + lq * 8);
            acc2[b] = __builtin_amdgcn_mfma_f32_16x16x32_bf16(af, bf, acc2[b], 0, 0, 0);
        }
    }
    float* Yg = Y + (size_t)bi * (64 * 32);
    for (int b = 0; b < 2; ++b) {
        int colk = b * 16 + lm;               // ky
        int mrow = wave * 16 + lq * 4;        // kx2
        for (int r = 0; r < 4; ++r)
            Yg[(mrow + r) * 32 + colk] = acc2[b][r];
    }
}

// ---------------- K2: channel mix (fp32), one block per (kx,ky) mode ----------------
// All 16 batches in one block: each weight element read by exactly one block.
// LDS: lW 16 KB + lY 8.3 KB = 24.7 KB -> grid fully resident (4 blocks/CU).
__global__ __launch_bounds__(256) void mix_kernel(const float* __restrict__ Wg,
                                                  const float* __restrict__ Y,
                                                  unsigned short* __restrict__ Mx) {
    __shared__ float lW[64 * 64];        // [i][o]            16 KB
    __shared__ float lY[16 * 130];       // [b][2i+c], pad+2   8.3 KB
    const int tid = threadIdx.x;
    // XCD-bijective swizzle (1024 % 8 == 0): all 32 ky of a kx on one XCD,
    // so 64B weight lines (16 consecutive ky) are fetched once.
    const int bid = blockIdx.x;
    const int mode = (bid & 7) * 128 + (bid >> 3);
    const int kx = mode >> 5, ky = mode & 31;

    // gather W[i][o][kx][ky] slice: 16 independent scattered loads/thread
    for (int q = 0; q < 16; ++q) {
        int e = q * 256 + tid;           // 0..4095 ; i = e>>6, o = e&63
        lW[e] = Wg[(size_t)e * 1024 + kx * 32 + ky];
    }
    // gather Y[b][i][2kx+c][ky] slice: 8 independent scattered loads/thread
    for (int q = 0; q < 8; ++q) {
        int e = q * 256 + tid;           // 0..2047
        int b = e >> 7, r = e & 127;     // r = 2i+c
        lY[b * 130 + r] = Y[(((size_t)b * 64 + (r >> 1)) * 64 + 2 * kx + (r & 1)) * 32 + ky];
    }
    __syncthreads();

    const int og = tid & 7;              // o block: og*8 .. og*8+7
    const int bc = tid >> 3;             // 0..31
    const int b = bc >> 1, c = bc & 1;
    float acc[8];
    for (int j = 0; j < 8; ++j) acc[j] = 0.f;
    for (int i = 0; i < 64; ++i) {       // same ascending-i order as before
        float yv = lY[b * 130 + 2 * i + c];
        const floatx4 w0 = *(const floatx4*)&lW[i * 64 + og * 8];
        const floatx4 w1 = *(const floatx4*)&lW[i * 64 + og * 8 + 4];
        acc[0] += yv * w0[0]; acc[1] += yv * w0[1];
        acc[2] += yv * w0[2]; acc[3] += yv * w0[3];
        acc[4] += yv * w1[0]; acc[5] += yv * w1[1];
        acc[6] += yv * w1[2]; acc[7] += yv * w1[3];
    }
    const float scale = 1.f / 65536.f;   // 1/(H*W): ifft+irfft normalization
    for (int j = 0; j < 8; ++j) {
        int o = og * 8 + j;
        Mx[((size_t)(b * 64 + o) * 64 + 2 * kx + c) * 32 + ky] = f2b(acc[j] * scale);
    }
}

// ---------------- K3: inverse, fused stages C+D, one block per (b,o) ----------------
// LDS: lMx 4KB (transposed to [ky][kx2]) + lZ 36KB = 40KB -> 4 blocks/CU.
__global__ __launch_bounds__(256) void inv_kernel(const unsigned short* __restrict__ ws_u,
                                                  const unsigned short* __restrict__ Mx,
                                                  const float* __restrict__ bias,
                                                  float* __restrict__ out) {
    __shared__ __align__(16) unsigned short lMx[32 * 64];   // 4 KB  [ky][kx2]
    __shared__ __align__(16) unsigned short lZ[256 * 72];   // 36 KB [h][ky2 padded]
    const int tid = threadIdx.x;
    const int wave = tid >> 6, lane = tid & 63;
    const int lm = lane & 15, lq = lane >> 4;
    const int bo = blockIdx.x;
    const int o = bo & 63;

    const unsigned short* G1g = ws_u + 49152;    // [512 h2][64 kx2], L2-resident
    const unsigned short* G2g = ws_u + 81920;    // [256 w][64 ky2],  L2-resident

    {   // stage Mx (layout [kx2][ky]) -> lMx transposed [ky][kx2]
        short8 v = *(const short8*)(Mx + (size_t)bo * 2048 + tid * 8);
        int kx2 = tid >> 2, kyb = (tid & 3) * 8;
        for (int e = 0; e < 8; ++e)
            lMx[(kyb + e) * 64 + kx2] = (unsigned short)v[e];
    }
    __syncthreads();

    // Stage C: Z2[512][32] = G1[512][64] x Mx2[64][32]; wave -> 8 m-tiles, 2 n-tiles
    {
        floatx4 accc[8][2];
        for (int a = 0; a < 8; ++a)
            for (int b = 0; b < 2; ++b) accc[a][b] = (floatx4){0.f, 0.f, 0.f, 0.f};
        for (int ks = 0; ks < 2; ++ks) {
            short8 bf[2];
            for (int b = 0; b < 2; ++b)
                bf[b] = *(const short8*)(lMx + (b * 16 + lm) * 64 + ks * 32 + lq * 8);
            for (int a = 0; a < 8; ++a) {
                int mt = wave * 8 + a;
                short8 af = *(const short8*)(G1g + (mt * 16 + lm) * 64 + ks * 32 + lq * 8);
                for (int b = 0; b < 2; ++b)
                    accc[a][b] = __builtin_amdgcn_mfma_f32_16x16x32_bf16(af, bf[b], accc[a][b], 0, 0, 0);
            }
        }
        // Z -> lZ [h][2ky+c]  (stage D's A-operand layout), padded stride 72
        for (int a = 0; a < 8; ++a) {
            int mbase = (wave * 8 + a) * 16 + lq * 4;
            for (int b = 0; b < 2; ++b) {
                int ky = b * 16 + lm;
                for (int r = 0; r < 4; ++r) {
                    int m = mbase + r;        // h2 = 2h + c
                    int h = m >> 1, c = m & 1;
                    lZ[h * 72 + 2 * ky + c] = f2b(accc[a][b][r]);
                }
            }
        }
    }
    __syncthreads();

    const float bv = bias[o];
    float* og = out + (size_t)bo * (H_ * W_);
    // Stage D: out[256][256] = Z2[256][64] x G2t'[64][256], in 4 h-strips of 64
    for (int s = 0; s < 4; ++s) {
        floatx4 accd[4][4];
        for (int a = 0; a < 4; ++a)
            for (int b = 0; b < 4; ++b) accd[a][b] = (floatx4){0.f, 0.f, 0.f, 0.f};
        for (int ks = 0; ks < 2; ++ks) {
            short8 af[4], bf[4];
            for (int a = 0; a < 4; ++a) {
                int mt = s * 4 + a;
                af[a] = *(const short8*)(lZ + (mt * 16 + lm) * 72 + ks * 32 + lq * 8);
            }
            for (int b = 0; b < 4; ++b) {
                int nt = wave * 4 + b;
                bf[b] = *(const short8*)(G2g + (nt * 16 + lm) * 64 + ks * 32 + lq * 8);
            }
            for (int a = 0; a < 4; ++a)
                for (int b = 0; b < 4; ++b)
                    accd[a][b] = __builtin_amdgcn_mfma_f32_16x16x32_bf16(af[a], bf[b], accd[a][b], 0, 0, 0);
        }
        for (int a = 0; a < 4; ++a) {
            int hbase = (s * 4 + a) * 16 + lq * 4;
            for (int b = 0; b < 4; ++b) {
                int w = (wave * 4 + b) * 16 + lm;
                for (int r = 0; r < 4; ++r)
                    og[(hbase + r) * 256 + w] = accd[a][b][r] + bv;
            }
        }
    }
}

extern "C" void kernel_launch(void* const* d_in, const int* in_sizes, int n_in,
                              void* d_out, int out_size, void* d_ws, size_t ws_size,
                              hipStream_t stream) {
    const float* x    = (const float*)d_in[0];
    const float* w    = (const float*)d_in[1];
    const float* bias = (const float*)d_in[2];
    float* out = (float*)d_out;
    unsigned short* ws_u = (unsigned short*)d_ws;
    float* Y = (float*)((char*)d_ws + 196608);
    unsigned short* Mx = (unsigned short*)((char*)d_ws + 8585216);

    build_tables<<<32, 256, 0, stream>>>(ws_u);
    fwd_kernel<<<1024, 256, 0, stream>>>(x, ws_u, Y);
    mix_kernel<<<1024, 256, 0, stream>>>(w, Y, Mx);
    inv_kernel<<<1024, 256, 0, stream>>>(ws_u, Mx, bias, out);
}

// Round 3
// 505.254 us; speedup vs baseline: 1.3394x; 1.0405x over previous
//
#include <hip/hip_runtime.h>

// SpectralConv2d as 4 dense partial-DFT GEMMs (bf16 MFMA) + fp32 channel mix.
// B=16, Cin=Cout=64, H=W=256, modes 32x32.
//
// Round-3: DRAM-efficiency pass (theory: fwd/inv at ~1.7 TB/s from 64-B
// scattered bursts; fill kernel proves 6.3 TB/s with contiguous runs).
//  * fwd: x staged via LDS in 64-row chunks; every global load instr is 1 KB
//    contiguous; cvt via v_cvt_pk_bf16_f32 (RNE, bit-identical to f2b);
//    F2t fragments hoisted to registers (reused across chunks).
//  * inv: output staged via LDS (32-row groups); every store instr is 1 KB
//    contiguous, 8-KB runs per wave. G2 fragments hoisted to registers.
//  * mix: W pre-transposed once (wtrans) -> coalesced W reads in mix.
//
// ws layout (bytes):
//   [0       ) F2t  ushort[64][256]   (32 KB)
//   [32768   ) F1e  ushort[64][512]   (64 KB)
//   [98304   ) G1   ushort[512][64]   (64 KB)
//   [163840  ) G2t  ushort[256][64]   (32 KB)
//   [196608  ) Y    float[16][64][64][32]  (8 MB)
//   [8585216 ) Mx   ushort[16][64][64][32] (4 MB)
//   [33554432) Wt   float[1024][4096]      (16 MB)  (ws is 1 GiB per harness fill)

#define H_ 256
#define W_ 256

typedef short short8 __attribute__((ext_vector_type(8)));
typedef float floatx4 __attribute__((ext_vector_type(4)));

static __device__ __forceinline__ unsigned short f2b(float f) {
    union { float f; unsigned int u; } v; v.f = f;
    unsigned int r = v.u + 0x7FFFu + ((v.u >> 16) & 1u);
    return (unsigned short)(r >> 16);
}

// packed fp32->bf16 RNE (identical rounding to f2b on finite inputs)
static __device__ __forceinline__ unsigned int cvt_pk_bf16(float a, float b) {
    unsigned int r;
    asm("v_cvt_pk_bf16_f32 %0, %1, %2" : "=v"(r) : "v"(a), "v"(b));
    return r;
}

// ---------------- K0: twiddle tables (fp64 -> bf16) ----------------
__global__ void build_tables(unsigned short* ws) {
    int k = blockIdx.x;      // mode index 0..31
    int n = threadIdx.x;     // position 0..255
    int u = (k * n) & 255;
    double ang = 6.283185307179586476925286766559 * (double)u / 256.0;
    float c = (float)cos(ang), s = (float)sin(ang);
    unsigned short bc = f2b(c), bs = f2b(s), bns = f2b(-s);
    unsigned short* F2t = ws;                    // [2ky+c][w]
    unsigned short* F1e = ws + 16384;            // [2kx+c][2h+c']
    unsigned short* G1  = ws + 16384 + 32768;    // [2h+c'][2kx+c]
    unsigned short* G2t = ws + 16384 + 65536;    // [w][2ky+c]

    F2t[(2 * k) * 256 + n]     = bc;
    F2t[(2 * k + 1) * 256 + n] = bns;
    F1e[(2 * k) * 512 + 2 * n]         = bc;
    F1e[(2 * k) * 512 + 2 * n + 1]     = bs;
    F1e[(2 * k + 1) * 512 + 2 * n]     = bns;
    F1e[(2 * k + 1) * 512 + 2 * n + 1] = bc;
    G1[(2 * n) * 64 + 2 * k]         = bc;
    G1[(2 * n) * 64 + 2 * k + 1]     = bns;
    G1[(2 * n + 1) * 64 + 2 * k]     = bs;
    G1[(2 * n + 1) * 64 + 2 * k + 1] = bc;
    float fac = (k == 0) ? 1.f : 2.f;
    G2t[n * 64 + 2 * k]     = f2b(fac * c);
    G2t[n * 64 + 2 * k + 1] = f2b(-fac * s);
}

// ---------------- K0b: W transpose [io][mode] -> [mode][io] ----------------
__global__ __launch_bounds__(256) void wtrans(const float* __restrict__ Wg,
                                              float* __restrict__ Wt) {
    __shared__ float t[64][65];
    const int iot = blockIdx.x;          // 0..63 (io tiles of 64)
    const int mt = blockIdx.y;           // 0..15 (mode tiles of 64)
    const int tid = threadIdx.x;
    for (int q = 0; q < 16; ++q) {
        int idx = q * 256 + tid;         // 64x64 tile
        int io = idx >> 6, m = idx & 63;
        t[io][m] = Wg[(size_t)(iot * 64 + io) * 1024 + mt * 64 + m];
    }
    __syncthreads();
    for (int q = 0; q < 16; ++q) {
        int idx = q * 256 + tid;
        int m = idx >> 6, io = idx & 63;
        Wt[(size_t)(mt * 64 + m) * 4096 + iot * 64 + io] = t[io][m];
    }
}

// ---------------- K1: forward, fused stages A+B, one block per (b,i) ----------------
// LDS: lA 33.8 KB (x chunk, contiguous-staged) + lT 32.5 KB = 66.3 KB -> 2 blocks/CU.
__global__ __launch_bounds__(256, 2) void fwd_kernel(const float* __restrict__ x,
                                                     const unsigned short* __restrict__ ws_u,
                                                     float* __restrict__ Y) {
    __shared__ __align__(16) unsigned short lA[64 * 264];   // [row][col pad+8]
    __shared__ __align__(16) unsigned short lT[32 * 520];   // [ky][h2 pad+8]
    const int tid = threadIdx.x;
    const int wave = tid >> 6, lane = tid & 63;
    const int lm = lane & 15, lq = lane >> 4;
    const int bi = blockIdx.x;

    const float* xg = x + (size_t)bi * (H_ * W_);
    const unsigned short* F2tg = ws_u;           // [64 ky2][256 w]
    const unsigned short* F1eg = ws_u + 16384;   // [64 kx2][512 h2]

    // hoist all F2t B-fragments (reused by every chunk): 8 kk x 4 b
    short8 bfA[8][4];
#pragma unroll
    for (int kk = 0; kk < 8; ++kk)
#pragma unroll
        for (int b = 0; b < 4; ++b)
            bfA[kk][b] = *(const short8*)(F2tg + (b * 16 + lm) * 256 + kk * 32 + lq * 8);

    floatx4 acc[4];
    // Stage A: T[h][ky2] = sum_w x[h][w] * F2t[ky2][w]; 4 chunks of 64 rows,
    // each chunk does the FULL K=256 (same K order as before: 32-col steps 0..7).
    for (int hc = 0; hc < 4; ++hc) {
        if (hc) __syncthreads();         // protect lA from previous chunk's readers
        // stage chunk: instr j covers one full 1-KB row contiguously
#pragma unroll
        for (int j = 0; j < 16; ++j) {
            int fi = j * 256 + tid;      // float4 index in [64][64]
            int row = fi >> 6, c4 = fi & 63;
            const float4 v = *(const float4*)(xg + (hc * 64 + row) * 256 + c4 * 4);
            uint2 p;
            p.x = cvt_pk_bf16(v.x, v.y);
            p.y = cvt_pk_bf16(v.z, v.w);
            *(uint2*)(lA + row * 264 + c4 * 4) = p;
        }
        __syncthreads();
#pragma unroll
        for (int b = 0; b < 4; ++b) acc[b] = (floatx4){0.f, 0.f, 0.f, 0.f};
#pragma unroll
        for (int kk = 0; kk < 8; ++kk) {
            short8 af = *(const short8*)(lA + (wave * 16 + lm) * 264 + kk * 32 + lq * 8);
#pragma unroll
            for (int b = 0; b < 4; ++b)
                acc[b] = __builtin_amdgcn_mfma_f32_16x16x32_bf16(af, bfA[kk][b], acc[b], 0, 0, 0);
        }
        // write T rows of this chunk into lT [ky][h2=2h+c]
#pragma unroll
        for (int b = 0; b < 4; ++b) {
            int col = b * 16 + lm;       // 2ky+c
            int ky = col >> 1, c = col & 1;
#pragma unroll
            for (int r = 0; r < 4; ++r) {
                int h = hc * 64 + wave * 16 + lq * 4 + r;
                lT[ky * 520 + 2 * h + c] = f2b(acc[b][r]);
            }
        }
    }
    __syncthreads();
    // Stage B: Y[64][32] = F1e[64][512] x T2[512][32]
    floatx4 acc2[2];
    acc2[0] = (floatx4){0.f, 0.f, 0.f, 0.f};
    acc2[1] = (floatx4){0.f, 0.f, 0.f, 0.f};
    for (int ks = 0; ks < 16; ++ks) {
        short8 af = *(const short8*)(F1eg + (wave * 16 + lm) * 512 + ks * 32 + lq * 8);
#pragma unroll
        for (int b = 0; b < 2; ++b) {
            short8 bf = *(const short8*)(lT + (b * 16 + lm) * 520 + ks * 32 + lq * 8);
            acc2[b] = __builtin_amdgcn_mfma_f32_16x16x32_bf16(af, bf, acc2[b], 0, 0, 0);
        }
    }
    float* Yg = Y + (size_t)bi * (64 * 32);
#pragma unroll
    for (int b = 0; b < 2; ++b) {
        int colk = b * 16 + lm;          // ky
        int mrow = wave * 16 + lq * 4;   // kx2
#pragma unroll
        for (int r = 0; r < 4; ++r)
            Yg[(mrow + r) * 32 + colk] = acc2[b][r];
    }
}

// ---------------- K2: channel mix (fp32), one block per (kx,ky) mode ----------------
__global__ __launch_bounds__(256) void mix_kernel(const float* __restrict__ Wt,
                                                  const float* __restrict__ Y,
                                                  unsigned short* __restrict__ Mx) {
    __shared__ float lW[64 * 64];        // [i][o]            16 KB
    __shared__ float lY[16 * 130];       // [b][2i+c], pad+2   8.3 KB
    const int tid = threadIdx.x;
    const int bid = blockIdx.x;
    const int mode = (bid & 7) * 128 + (bid >> 3);   // XCD-bijective swizzle
    const int kx = mode >> 5, ky = mode & 31;

    // W slice now contiguous in Wt[mode][io]: fully coalesced
    {
        const float4* src = (const float4*)(Wt + (size_t)mode * 4096);
        float4* dst = (float4*)lW;
        for (int q = 0; q < 4; ++q) dst[q * 256 + tid] = src[q * 256 + tid];
    }
    // gather Y[b][i][2kx+c][ky] slice
    for (int q = 0; q < 8; ++q) {
        int e = q * 256 + tid;           // 0..2047
        int b = e >> 7, r = e & 127;     // r = 2i+c
        lY[b * 130 + r] = Y[(((size_t)b * 64 + (r >> 1)) * 64 + 2 * kx + (r & 1)) * 32 + ky];
    }
    __syncthreads();

    const int og = tid & 7;              // o block: og*8 .. og*8+7
    const int bc = tid >> 3;             // 0..31
    const int b = bc >> 1, c = bc & 1;
    float acc[8];
#pragma unroll
    for (int j = 0; j < 8; ++j) acc[j] = 0.f;
    for (int i = 0; i < 64; ++i) {       // same ascending-i order
        float yv = lY[b * 130 + 2 * i + c];
        const floatx4 w0 = *(const floatx4*)&lW[i * 64 + og * 8];
        const floatx4 w1 = *(const floatx4*)&lW[i * 64 + og * 8 + 4];
        acc[0] += yv * w0[0]; acc[1] += yv * w0[1];
        acc[2] += yv * w0[2]; acc[3] += yv * w0[3];
        acc[4] += yv * w1[0]; acc[5] += yv * w1[1];
        acc[6] += yv * w1[2]; acc[7] += yv * w1[3];
    }
    const float scale = 1.f / 65536.f;   // 1/(H*W)
#pragma unroll
    for (int j = 0; j < 8; ++j) {
        int o = og * 8 + j;
        Mx[((size_t)(b * 64 + o) * 64 + 2 * kx + c) * 32 + ky] = f2b(acc[j] * scale);
    }
}

// ---------------- K3: inverse, fused stages C+D, one block per (b,o) ----------------
// LDS: lMx 4 KB + lZ 36 KB + lOut 33.3 KB = 73.2 KB -> 2 blocks/CU.
__global__ __launch_bounds__(256, 2) void inv_kernel(const unsigned short* __restrict__ ws_u,
                                                     const unsigned short* __restrict__ Mx,
                                                     const float* __restrict__ bias,
                                                     float* __restrict__ out) {
    __shared__ __align__(16) unsigned short lMx[32 * 64];   // 4 KB  [ky][kx2]
    __shared__ __align__(16) unsigned short lZ[256 * 72];   // 36 KB [h][ky2 pad]
    __shared__ __align__(16) float lOut[32 * 260];          // 33.3 KB [row][col pad+4]
    const int tid = threadIdx.x;
    const int wave = tid >> 6, lane = tid & 63;
    const int lm = lane & 15, lq = lane >> 4;
    const int bo = blockIdx.x;
    const int o = bo & 63;

    const unsigned short* G1g = ws_u + 49152;    // [512 h2][64 kx2]
    const unsigned short* G2g = ws_u + 81920;    // [256 w][64 ky2]
    const float bv = bias[o];

    // hoist G2 B-fragments (reused across all 4 strips): 2 ks x 4 b
    short8 bfD[2][4];
#pragma unroll
    for (int ks = 0; ks < 2; ++ks)
#pragma unroll
        for (int b = 0; b < 4; ++b)
            bfD[ks][b] = *(const short8*)(G2g + ((wave * 4 + b) * 16 + lm) * 64 + ks * 32 + lq * 8);

    {   // stage Mx (layout [kx2][ky]) -> lMx transposed [ky][kx2]
        short8 v = *(const short8*)(Mx + (size_t)bo * 2048 + tid * 8);
        int kx2 = tid >> 2, kyb = (tid & 3) * 8;
#pragma unroll
        for (int e = 0; e < 8; ++e)
            lMx[(kyb + e) * 64 + kx2] = (unsigned short)v[e];
    }
    __syncthreads();

    // Stage C: Z2[512][32] = G1[512][64] x Mx2[64][32]
    {
        floatx4 accc[8][2];
#pragma unroll
        for (int a = 0; a < 8; ++a)
#pragma unroll
            for (int b = 0; b < 2; ++b) accc[a][b] = (floatx4){0.f, 0.f, 0.f, 0.f};
#pragma unroll
        for (int ks = 0; ks < 2; ++ks) {
            short8 bf[2];
#pragma unroll
            for (int b = 0; b < 2; ++b)
                bf[b] = *(const short8*)(lMx + (b * 16 + lm) * 64 + ks * 32 + lq * 8);
#pragma unroll
            for (int a = 0; a < 8; ++a) {
                int mt = wave * 8 + a;
                short8 af = *(const short8*)(G1g + (mt * 16 + lm) * 64 + ks * 32 + lq * 8);
#pragma unroll
                for (int b = 0; b < 2; ++b)
                    accc[a][b] = __builtin_amdgcn_mfma_f32_16x16x32_bf16(af, bf[b], accc[a][b], 0, 0, 0);
            }
        }
        // Z -> lZ [h][2ky+c]
#pragma unroll
        for (int a = 0; a < 8; ++a) {
            int mbase = (wave * 8 + a) * 16 + lq * 4;
#pragma unroll
            for (int b = 0; b < 2; ++b) {
                int ky = b * 16 + lm;
#pragma unroll
                for (int r = 0; r < 4; ++r) {
                    int m = mbase + r;        // h2 = 2h + c
                    int h = m >> 1, c = m & 1;
                    lZ[h * 72 + 2 * ky + c] = f2b(accc[a][b][r]);
                }
            }
        }
    }
    __syncthreads();

    float* og = out + (size_t)bo * (H_ * W_);
    // Stage D: out[256][256] = Z2[256][64] x G2t'[64][256], 4 h-strips of 64;
    // epilogue staged through lOut in 32-row groups -> 1-KB-contiguous stores.
    for (int s = 0; s < 4; ++s) {
        floatx4 accd[4][4];
#pragma unroll
        for (int a = 0; a < 4; ++a)
#pragma unroll
            for (int b = 0; b < 4; ++b) accd[a][b] = (floatx4){0.f, 0.f, 0.f, 0.f};
#pragma unroll
        for (int ks = 0; ks < 2; ++ks) {
            short8 af[4];
#pragma unroll
            for (int a = 0; a < 4; ++a) {
                int mt = s * 4 + a;
                af[a] = *(const short8*)(lZ + (mt * 16 + lm) * 72 + ks * 32 + lq * 8);
            }
#pragma unroll
            for (int a = 0; a < 4; ++a)
#pragma unroll
                for (int b = 0; b < 4; ++b)
                    accd[a][b] = __builtin_amdgcn_mfma_f32_16x16x32_bf16(af[a], bfD[ks][b], accd[a][b], 0, 0, 0);
        }
        for (int g = 0; g < 2; ++g) {    // 32-row halves of the strip
            __syncthreads();             // protect lOut reuse
#pragma unroll
            for (int a2 = 0; a2 < 2; ++a2) {
                int a = g * 2 + a2;
#pragma unroll
                for (int b = 0; b < 4; ++b) {
                    int col = wave * 64 + b * 16 + lm;
#pragma unroll
                    for (int r = 0; r < 4; ++r) {
                        int row = a2 * 16 + lq * 4 + r;
                        lOut[row * 260 + col] = accd[a][b][r] + bv;
                    }
                }
            }
            __syncthreads();
#pragma unroll
            for (int j = 0; j < 8; ++j) {
                int row = wave * 8 + j;
                floatx4 v = *(const floatx4*)(lOut + row * 260 + lane * 4);
                *(floatx4*)(og + (s * 64 + g * 32 + row) * 256 + lane * 4) = v;
            }
        }
    }
}

extern "C" void kernel_launch(void* const* d_in, const int* in_sizes, int n_in,
                              void* d_out, int out_size, void* d_ws, size_t ws_size,
                              hipStream_t stream) {
    const float* x    = (const float*)d_in[0];
    const float* w    = (const float*)d_in[1];
    const float* bias = (const float*)d_in[2];
    float* out = (float*)d_out;
    unsigned short* ws_u = (unsigned short*)d_ws;
    float* Y  = (float*)((char*)d_ws + 196608);
    unsigned short* Mx = (unsigned short*)((char*)d_ws + 8585216);
    float* Wt = (float*)((char*)d_ws + 33554432);

    build_tables<<<32, 256, 0, stream>>>(ws_u);
    wtrans<<<dim3(64, 16), 256, 0, stream>>>(w, Wt);
    fwd_kernel<<<1024, 256, 0, stream>>>(x, ws_u, Y);
    mix_kernel<<<1024, 256, 0, stream>>>(Wt, Y, Mx);
    inv_kernel<<<1024, 256, 0, stream>>>(ws_u, Mx, bias, out);
}